// Round 1
// baseline (276.922 us; speedup 1.0000x reference)
//
#include <hip/hip_runtime.h>
#include <hip/hip_bf16.h>

// Problem constants
#define Dm   1024
#define Hh   16
#define HDq  64
#define DKV  512
#define KVHD 32
#define HID  128
#define Bb   2
#define Ll   2048
#define Ff   32

__device__ __forceinline__ float gelu_exact(float x) {
    return 0.5f * x * (1.0f + erff(x * 0.70710678118654752f));
}

// ---------------------------------------------------------------------------
// Kernel 1: per-batch scalars at position L-1: tau, delta_last, Qc -> w_comb
// w_comb[b][c] = tau[b] * Qc[b][c] / sqrt(32) + delta_last[b][c]
// ---------------------------------------------------------------------------
__global__ __launch_bounds__(256) void k_setup(
        const float* __restrict__ h,
        const float* __restrict__ mu,
        const float* __restrict__ sigma,
        const float* __restrict__ Wq,
        const float* __restrict__ tau_w1, const float* __restrict__ tau_b1,
        const float* __restrict__ tau_w2, const float* __restrict__ tau_b2,
        const float* __restrict__ del_w1, const float* __restrict__ del_b1,
        const float* __restrict__ del_w2, const float* __restrict__ del_b2,
        float* __restrict__ w_comb)
{
    const int b = blockIdx.x;
    const int tid = threadIdx.x;
    __shared__ float hl[Dm];
    __shared__ float gh[HID];     // gelu(delta hidden)
    __shared__ float red[256];
    __shared__ float s_tau, s_smean, s_mmean;

    const float* hrow = h + ((size_t)b * Ll + (Ll - 1)) * Dm;
    for (int j = tid; j < Dm; j += 256) hl[j] = hrow[j];
    if (tid == 0) {
        float s = 0.f;
        for (int f = 0; f < Ff; ++f) s += sigma[((size_t)b * Ll + (Ll - 1)) * Ff + f];
        s /= (float)Ff;
        s_smean = fmaxf(s, 1e-6f);
    }
    if (tid == 1) {
        float s = 0.f;
        for (int f = 0; f < Ff; ++f) s += mu[((size_t)b * Ll + (Ll - 1)) * Ff + f];
        s_mmean = s / (float)Ff;
    }
    __syncthreads();

    // hidden layers of both MLPs (128 threads active)
    if (tid < HID) {
        float a  = tau_b1[tid] + s_smean * tau_w1[tid];
        float ad = del_b1[tid] + s_mmean * del_w1[tid];
        for (int j = 0; j < Dm; ++j) {
            float x = hl[j];
            a  += x * tau_w1[(size_t)(j + 1) * HID + tid];
            ad += x * del_w1[(size_t)(j + 1) * HID + tid];
        }
        gh[tid]  = gelu_exact(ad);
        red[tid] = gelu_exact(a) * tau_w2[tid];
    }
    __syncthreads();
    if (tid == 0) {
        float s = 0.f;
        for (int i = 0; i < HID; ++i) s += red[i];
        s += tau_b2[0];
        s = fminf(fmaxf(s, -3.f), 3.f);
        s_tau = expf(s);
    }
    __syncthreads();

    const float inv_sqrt = 0.17677669529663687f; // 1/sqrt(32)
    for (int c = tid; c < DKV; c += 256) {
        float dacc = del_b2[c];
        for (int i = 0; i < HID; ++i) dacc += gh[i] * del_w2[(size_t)i * DKV + c];
        dacc = fminf(fmaxf(dacc, -5.f), 5.f);
        const int head = c >> 5, d = c & 31;
        const int col = head * HDq + d;     // Qc column in Wq
        float q = 0.f;
        for (int j = 0; j < Dm; ++j) q += hl[j] * Wq[(size_t)j * Dm + col];
        w_comb[(size_t)b * DKV + c] = s_tau * q * inv_sqrt + dacc;
    }
}

// ---------------------------------------------------------------------------
// Kernel 2: K/V GEMM.  A = h (4096 x 1024), B = [Wk | Wv] (1024 x 1024).
// ntile < 8 -> K region: fuse logits (dot with w_comb), don't store K.
// ntile >= 8 -> V region: store V tile to workspace.
// ---------------------------------------------------------------------------
#define BM 64
#define BN 64
#define BKK 16
#define LPAD 68

__global__ __launch_bounds__(256) void k_kv(
        const float* __restrict__ hmat,
        const float* __restrict__ Wk, const float* __restrict__ Wv,
        const float* __restrict__ w_comb,
        float* __restrict__ Vws, float* __restrict__ logits)
{
    const int ntile = blockIdx.x;   // 0..15
    const int mtile = blockIdx.y;   // 0..63
    const int tid = threadIdx.x;

    __shared__ __align__(16) float As[BKK][LPAD];
    __shared__ __align__(16) float Bs[BKK][LPAD];
    __shared__ __align__(16) float Cs[BM][LPAD];
    __shared__ float wc[BN];

    const int gr0 = mtile * BM;           // global row in [0, B*L)
    const int b = gr0 >> 11;              // / 2048
    const float* A = hmat + (size_t)gr0 * Dm;
    const bool isK = ntile < 8;
    const float* Bmat = isK ? Wk : Wv;
    const int n0 = isK ? ntile * BN : ntile * BN - DKV;

    const int tx = tid & 15, ty = tid >> 4;
    const int ar = tid >> 2;              // 0..63 (row for A load)
    const int aq = (tid & 3) * 4;         // k-quad for A load
    const int bk = tid >> 4;              // 0..15 (k row for B load)
    const int bq = (tid & 15) * 4;        // col-quad for B load

    float acc[4][4] = {};

    for (int kt = 0; kt < Dm / BKK; ++kt) {
        const int k0 = kt * BKK;
        float4 av = *(const float4*)(A + (size_t)ar * Dm + k0 + aq);
        As[aq + 0][ar] = av.x; As[aq + 1][ar] = av.y;
        As[aq + 2][ar] = av.z; As[aq + 3][ar] = av.w;
        float4 bv = *(const float4*)(Bmat + (size_t)(k0 + bk) * DKV + n0 + bq);
        *(float4*)(&Bs[bk][bq]) = bv;
        __syncthreads();
#pragma unroll
        for (int k = 0; k < BKK; ++k) {
            float a0 = As[k][ty * 4 + 0], a1 = As[k][ty * 4 + 1];
            float a2 = As[k][ty * 4 + 2], a3 = As[k][ty * 4 + 3];
            float b0 = Bs[k][tx * 4 + 0], b1 = Bs[k][tx * 4 + 1];
            float b2 = Bs[k][tx * 4 + 2], b3 = Bs[k][tx * 4 + 3];
            acc[0][0] += a0 * b0; acc[0][1] += a0 * b1; acc[0][2] += a0 * b2; acc[0][3] += a0 * b3;
            acc[1][0] += a1 * b0; acc[1][1] += a1 * b1; acc[1][2] += a1 * b2; acc[1][3] += a1 * b3;
            acc[2][0] += a2 * b0; acc[2][1] += a2 * b1; acc[2][2] += a2 * b2; acc[2][3] += a2 * b3;
            acc[3][0] += a3 * b0; acc[3][1] += a3 * b1; acc[3][2] += a3 * b2; acc[3][3] += a3 * b3;
        }
        __syncthreads();
    }

    if (!isK) {
        // store V tile (coalesced-ish float4 per row)
#pragma unroll
        for (int i = 0; i < 4; ++i) {
            const int gl = gr0 + ty * 4 + i;   // global row = b*L + l
            float4 v = make_float4(acc[i][0], acc[i][1], acc[i][2], acc[i][3]);
            *(float4*)(Vws + (size_t)gl * DKV + n0 + tx * 4) = v;
        }
    } else {
        // stage K tile to LDS, then fused logits dot with w_comb
#pragma unroll
        for (int i = 0; i < 4; ++i)
#pragma unroll
            for (int j = 0; j < 4; ++j)
                Cs[ty * 4 + i][tx * 4 + j] = acc[i][j];
        if (tid < BN) wc[tid] = w_comb[(size_t)b * DKV + ntile * BN + tid];
        __syncthreads();
        if (tid < 128) {
            const int row = tid >> 1, hh = tid & 1;
            float s = 0.f;
#pragma unroll
            for (int d = 0; d < 32; ++d) s += Cs[row][hh * 32 + d] * wc[hh * 32 + d];
            s = fminf(fmaxf(s, -50.f), 50.f);
            const int head = ntile * 2 + hh;
            const int l = (gr0 & (Ll - 1)) + row;
            logits[((size_t)b * Hh + head) * Ll + l] = s;
        }
    }
}

// ---------------------------------------------------------------------------
// Kernel 3: per (b,h): softmax over 2048 keys + weighted sum of V -> out_pre
// ---------------------------------------------------------------------------
__global__ __launch_bounds__(256) void k_attn(
        const float* __restrict__ logits,
        const float* __restrict__ Vws,
        float* __restrict__ out_pre)
{
    const int bh = blockIdx.x;            // b*16 + h
    const int b = bh >> 4, hd = bh & 15;
    const int tid = threadIdx.x;

    __shared__ float p[Ll];
    __shared__ float red[256];
    __shared__ float part[4][32];

    const float* lg = logits + (size_t)bh * Ll;
    float lv[8];
    float lmax = -1e30f;
#pragma unroll
    for (int i = 0; i < 8; ++i) { lv[i] = lg[tid + i * 256]; lmax = fmaxf(lmax, lv[i]); }
    red[tid] = lmax; __syncthreads();
    for (int s = 128; s > 0; s >>= 1) { if (tid < s) red[tid] = fmaxf(red[tid], red[tid + s]); __syncthreads(); }
    lmax = red[0];
    __syncthreads();
    float lsum = 0.f;
#pragma unroll
    for (int i = 0; i < 8; ++i) { float e = expf(lv[i] - lmax); p[tid + i * 256] = e; lsum += e; }
    red[tid] = lsum; __syncthreads();
    for (int s = 128; s > 0; s >>= 1) { if (tid < s) red[tid] += red[tid + s]; __syncthreads(); }
    const float inv_den = 1.0f / red[0];

    float acc[32];
#pragma unroll
    for (int d = 0; d < 32; ++d) acc[d] = 0.f;
    const float* Vb = Vws + ((size_t)b * Ll) * DKV + hd * 32;
    for (int l = tid; l < Ll; l += 256) {
        const float pl = p[l];
        const float4* vr = (const float4*)(Vb + (size_t)l * DKV);
#pragma unroll
        for (int q = 0; q < 8; ++q) {
            float4 v = vr[q];
            acc[q * 4 + 0] += pl * v.x; acc[q * 4 + 1] += pl * v.y;
            acc[q * 4 + 2] += pl * v.z; acc[q * 4 + 3] += pl * v.w;
        }
    }
    const int lane = tid & 63, wv = tid >> 6;
#pragma unroll
    for (int d = 0; d < 32; ++d) {
        float v = acc[d];
        for (int off = 32; off > 0; off >>= 1) v += __shfl_down(v, off);
        if (lane == 0) part[wv][d] = v;
    }
    __syncthreads();
    if (tid < 32) {
        float s = part[0][tid] + part[1][tid] + part[2][tid] + part[3][tid];
        out_pre[(size_t)bh * 32 + tid] = s * inv_den;
    }
}

// ---------------------------------------------------------------------------
// Kernel 4: out[b] = out_pre[b] @ Wo + bo   (B x 512) @ (512 x 1024)
// ---------------------------------------------------------------------------
__global__ __launch_bounds__(256) void k_out(
        const float* __restrict__ out_pre,
        const float* __restrict__ Wo, const float* __restrict__ bo,
        float* __restrict__ out)
{
    const int b = blockIdx.y;
    const int n = blockIdx.x * 256 + threadIdx.x;
    __shared__ float op[DKV];
    for (int c = threadIdx.x; c < DKV; c += 256) op[c] = out_pre[(size_t)b * DKV + c];
    __syncthreads();
    float acc = bo[n];
    for (int c = 0; c < DKV; ++c) acc += op[c] * Wo[(size_t)c * Dm + n];
    out[(size_t)b * Dm + n] = acc;
}

// ---------------------------------------------------------------------------
extern "C" void kernel_launch(void* const* d_in, const int* in_sizes, int n_in,
                              void* d_out, int out_size, void* d_ws, size_t ws_size,
                              hipStream_t stream) {
    const float* h      = (const float*)d_in[0];
    const float* mu     = (const float*)d_in[1];
    const float* sigma  = (const float*)d_in[2];
    const float* Wq     = (const float*)d_in[3];
    const float* Wk     = (const float*)d_in[4];
    const float* Wv     = (const float*)d_in[5];
    const float* Wo     = (const float*)d_in[6];
    const float* bo     = (const float*)d_in[7];
    const float* tau_w1 = (const float*)d_in[8];
    const float* tau_b1 = (const float*)d_in[9];
    const float* tau_w2 = (const float*)d_in[10];
    const float* tau_b2 = (const float*)d_in[11];
    const float* del_w1 = (const float*)d_in[12];
    const float* del_b1 = (const float*)d_in[13];
    const float* del_w2 = (const float*)d_in[14];
    const float* del_b2 = (const float*)d_in[15];
    float* out = (float*)d_out;

    // workspace layout (floats)
    float* ws = (float*)d_ws;
    float* Vws     = ws;                               // B*L*DKV   = 2,097,152
    float* logits  = Vws + (size_t)Bb * Ll * DKV;      // B*H*L     = 65,536
    float* w_comb  = logits + (size_t)Bb * Hh * Ll;    // B*DKV     = 1,024
    float* out_pre = w_comb + (size_t)Bb * DKV;        // B*DKV     = 1,024

    k_setup<<<Bb, 256, 0, stream>>>(h, mu, sigma, Wq, tau_w1, tau_b1, tau_w2, tau_b2,
                                    del_w1, del_b1, del_w2, del_b2, w_comb);
    k_kv<<<dim3(16, 64), 256, 0, stream>>>(h, Wk, Wv, w_comb, Vws, logits);
    k_attn<<<Bb * Hh, 256, 0, stream>>>(logits, Vws, out_pre);
    k_out<<<dim3(Dm / 256, Bb), 256, 0, stream>>>(out_pre, Wo, bo, out);
}